// Round 8
// baseline (287.145 us; speedup 1.0000x reference)
//
#include <hip/hip_runtime.h>
#include <stdint.h>

#define B_   16
#define N_   16128
#define C_   85
#define K_   500
#define KP   512
#define APB  128
#define HB   4096          // histogram bins = score bits [22:11]
#define CAND 1024
#define NSTRIP 2304        // sum over rows i of (wave(i)+1); triangular Pg strips/image

__device__ __forceinline__ float sigm(float x){
  return __fdividef(1.0f, 1.0f + __expf(-x));
}
__device__ __forceinline__ float pfun(float4 a, float4 b, float areaA){
  float x1 = fmaxf(a.x, b.x), y1 = fmaxf(a.y, b.y);
  float x2 = fminf(a.z, b.z), y2 = fminf(a.w, b.w);
  float inter = fmaxf(x2 - x1, 0.f) * fmaxf(y2 - y1, 0.f);
  float areaB = fmaxf(b.z - b.x, 0.f) * fmaxf(b.w - b.y, 0.f);
  float uni = areaA + areaB - inter;
  float iou = __fdividef(inter, fmaxf(uni, 1e-9f));
  return __fdividef(1.0f, 1.0f + __expf((0.4f - iou) * 10.0f));
}
__device__ __forceinline__ unsigned binof(unsigned sb){ return (sb >> 11) & (HB-1); }
// triangular strip base for row i (w = i>>6): strips for d=0..w at base(i)+d
__device__ __forceinline__ int stripbase(int i){ int w = i >> 6; return (w+1)*(i - 32*w); }

// ---------------- Stage 1: scores (pipelined staging) + fused global histogram ----
__global__ __launch_bounds__(256) void k_scores(const float* __restrict__ preds,
                                                float* __restrict__ scores,
                                                unsigned* __restrict__ hist){
  __shared__ float lds[APB*C_];            // 10880 floats = 2720 float4
  const int tid = threadIdx.x;
  const size_t blockBase = (size_t)blockIdx.x * (APB*C_);
  const float4* g4 = (const float4*)(preds + blockBase);
  float4* l4 = (float4*)lds;

  float4 t[10];
  #pragma unroll
  for (int k = 0; k < 10; ++k) t[k] = g4[tid + k*256];
  const bool extra = (tid < 160);
  float4 tx = extra ? g4[2560 + tid] : make_float4(0.f,0.f,0.f,0.f);
  #pragma unroll
  for (int k = 0; k < 10; ++k) l4[tid + k*256] = t[k];
  if (extra) l4[2560 + tid] = tx;
  __syncthreads();

  if (tid < APB){
    const float* row = lds + tid*C_;
    float m = row[1];
    #pragma unroll
    for (int c=2; c<C_; ++c) m = fmaxf(m, row[c]);
    const int g = blockIdx.x*APB + tid;
    scores[g] = m;
    atomicAdd(&hist[(g / N_)*HB + binof(__float_as_uint(m))], 1u);
  }
}

// ---------------- Stage 2: exact top-500: cutoff from hist, compact, rank-sort ----
__global__ __launch_bounds__(256) void k_compact(const float* __restrict__ scores,
                                                 const unsigned* __restrict__ hist,
                                                 const float* __restrict__ boxes,
                                                 const int*   __restrict__ targets,
                                                 float* __restrict__ sscore,  // [B][K]
                                                 float* __restrict__ gbox,    // [B][KP][4], rows>=K zero
                                                 float* __restrict__ gtgt){   // [B][K]
  __shared__ unsigned long long keybuf[CAND];   // 8 KB
  __shared__ unsigned long long sorted[KP];     // 4 KB
  __shared__ unsigned part[256];
  __shared__ unsigned s_bsel;
  __shared__ unsigned s_cnt;
  const int img = blockIdx.x;
  const int tid = threadIdx.x;
  const unsigned* hi = hist + img*HB;
  const float* sc = scores + (size_t)img*N_;

  // suffix-scan the 4096-bin histogram; thread t owns bins [16t,16t+16)
  unsigned loc[16]; unsigned psum = 0;
  #pragma unroll
  for (int q = 0; q < 16; ++q){ loc[q] = hi[tid*16 + q]; psum += loc[q]; }
  part[tid] = psum;
  if (tid == 0) s_cnt = 0;
  __syncthreads();
  for (int off = 1; off < 256; off <<= 1){
    unsigned add = (tid + off < 256) ? part[tid + off] : 0;
    __syncthreads();
    part[tid] += add;
    __syncthreads();
  }
  const unsigned St  = part[tid];
  const unsigned St1 = (tid < 255) ? part[tid+1] : 0;
  if (St >= K_ && (tid == 255 || St1 < K_)){
    unsigned cum = St1; int b = tid*16;
    for (int q = 15; q >= 0; --q){
      cum += loc[q];
      if (cum >= K_){ b = tid*16 + q; break; }
    }
    s_bsel = (unsigned)b;
  }
  __syncthreads();
  const unsigned bsel = s_bsel;

  // compact candidates: all elements with bin >= bsel (cnt in [500, ~800])
  for (int n = tid; n < N_; n += 256){
    unsigned sb = __float_as_uint(sc[n]);
    if (binof(sb) >= bsel){
      unsigned pos = atomicAdd(&s_cnt, 1u);
      if (pos < CAND)
        keybuf[pos] = ((unsigned long long)sb << 14) | (unsigned long long)(N_ - 1 - n);
    }
  }
  __syncthreads();
  const int cnt = (int)min(s_cnt, (unsigned)CAND);
  for (int i = tid; i < CAND; i += 256) if (i >= cnt) keybuf[i] = 0ULL;
  __syncthreads();

  // exact rank-sort: keys unique; rank = #{keys > mine}; broadcast walk of keybuf
  unsigned long long myk[4];
  int myr[4] = {0,0,0,0};
  #pragma unroll
  for (int q = 0; q < 4; ++q) myk[q] = keybuf[tid + q*256];
  for (int j = 0; j < cnt; ++j){
    unsigned long long kj = keybuf[j];   // same address all threads: LDS broadcast
    #pragma unroll
    for (int q = 0; q < 4; ++q) myr[q] += (myk[q] < kj) ? 1 : 0;
  }
  #pragma unroll
  for (int q = 0; q < 4; ++q) if (myr[q] < K_) sorted[myr[q]] = myk[q];
  __syncthreads();

  for (int r = tid; r < K_; r += 256){
    unsigned long long key = sorted[r];
    unsigned sb = (unsigned)(key >> 14);
    unsigned n  = (unsigned)(N_ - 1 - (int)(key & 0x3FFFULL));
    sscore[img*K_ + r] = __uint_as_float(sb);
    ((float4*)gbox)[img*KP + r] = ((const float4*)boxes)[(size_t)img*N_ + n];
    gtgt[img*K_ + r] = (float)targets[(size_t)img*N_ + n];
  }
  if (tid < KP - K_)
    ((float4*)gbox)[img*KP + K_ + tid] = make_float4(0.f,0.f,0.f,0.f);
}

// ---------------- Stage 3a: masked prune matrix, triangular-packed ----------------
// strip (i,d), d<=wave(i): Pg[(img*NSTRIP + stripbase(i)+d)*64 + jj]
//   = (d*64+jj < i) ? prune(b_i, b_{d*64+jj}) : 0
__global__ __launch_bounds__(256) void k_iou(const float* __restrict__ gbox,
                                             float* __restrict__ Pg){
  __shared__ float4 bcol[64];
  const int img = blockIdx.x, d = blockIdx.y, half = blockIdx.z;
  const int tid = threadIdx.x;
  const int i = half*256 + tid;
  if ((half+1)*256 <= d*64) return;        // whole block below diagonal band
  if (tid < 64) bcol[tid] = ((const float4*)gbox)[img*KP + d*64 + tid];
  __syncthreads();
  if (i < d*64) return;                    // row never read by k_nms
  float4 bi = ((const float4*)gbox)[img*KP + i];
  const float areai = fmaxf(bi.z-bi.x,0.f)*fmaxf(bi.w-bi.y,0.f);
  float4* dst = (float4*)(Pg + ((size_t)img*NSTRIP + stripbase(i) + d)*64);
  #pragma unroll
  for (int q = 0; q < 16; ++q){
    float4 o;
    float* op = (float*)&o;
    #pragma unroll
    for (int s = 0; s < 4; ++s){
      int jj = q*4 + s;
      float p = pfun(bi, bcol[jj], areai);
      op[s] = (d*64 + jj < i) ? p : 0.0f;
    }
    dst[q] = o;
  }
}

// ---------------- Stage 3b: diff-NMS forward substitution ----------------
__global__ __launch_bounds__(512) void k_nms(const float* __restrict__ sscore,
                                             const float* __restrict__ Pg,
                                             float* __restrict__ vout,   // [B][KP]
                                             float* __restrict__ acc,    // [B][2]
                                             unsigned* __restrict__ done){
  __shared__ float vsh[KP];
  const int img  = blockIdx.x;
  const int tid  = threadIdx.x;
  const int wave = tid >> 6;

  float rr = (tid < K_) ? sscore[img*K_ + tid] : 0.0f;
  float v  = 0.0f;
  if (tid < 2) acc[2*img + tid] = 0.0f;
  if (img == 0 && tid == 2) *done = 0;

  const float* stripRow = Pg + ((size_t)img*NSTRIP + stripbase(tid))*64;  // +d*64 per phase

  for (int d = 0; d < 8; ++d){
    if (wave == d){
      const float4* strip = (const float4*)(stripRow + (size_t)d*64);
      float4 p4[16];
      #pragma unroll
      for (int q = 0; q < 16; ++q) p4[q] = strip[q];
      const float* p = (const float*)p4;
      #pragma unroll
      for (int j = 0; j < 64; ++j){
        float c = fminf(fmaxf(rr, 0.0f), 1.0f);
        float vj = __int_as_float(__builtin_amdgcn_readlane(__float_as_int(c), j));
        rr -= p[j] * vj;
      }
      v = fminf(fmaxf(rr, 0.0f), 1.0f);
      vsh[tid] = v;
    }
    __syncthreads();
    if (wave > d){
      const float4* strip = (const float4*)(stripRow + (size_t)d*64);
      const float4* vv = (const float4*)(vsh + d*64);
      float s0 = 0.f, s1 = 0.f;
      #pragma unroll
      for (int q = 0; q < 16; ++q){
        float4 pq = strip[q];
        float4 vq = vv[q];
        s0 += pq.x*vq.x + pq.y*vq.y;
        s1 += pq.z*vq.z + pq.w*vq.w;
      }
      rr -= (s0 + s1);
    }
  }
  vout[img*KP + tid] = v;
}

// ---------------- Stage 4+5: AP loss + fused final reduction ----------------
__global__ __launch_bounds__(128) void k_ap(const float* __restrict__ vout,
                                            const float* __restrict__ gtgt,
                                            float* __restrict__ acc,
                                            unsigned* __restrict__ done,
                                            float* __restrict__ out){
  __shared__ float vls[K_];
  __shared__ float yls[K_];
  __shared__ float red[4];
  const int img = blockIdx.x;
  const int seg = blockIdx.y;
  const int tid = threadIdx.x;

  for (int j = tid; j < K_; j += 128){
    vls[j] = vout[img*KP + j];
    yls[j] = gtgt[img*K_ + j];
  }
  __syncthreads();

  const int i = seg*125 + tid;
  float contrib = 0.f, ypos = 0.f;
  if (tid < 125){
    const float vi = vls[i];
    const float yi = yls[i];
    float rank = 0.f, posr = 0.f;
    #pragma unroll 4
    for (int j = 0; j < K_; ++j){
      float h = sigm((vls[j] - vi) * 20.0f);
      float hm = (j == i) ? 0.0f : h;
      rank += hm;
      posr += hm * yls[j];
    }
    float prec = __fdividef(1.0f + posr, 1.0f + rank);
    contrib = prec * yi;
    ypos = yi;
  }
  #pragma unroll
  for (int off = 32; off > 0; off >>= 1){
    contrib += __shfl_xor(contrib, off, 64);
    ypos    += __shfl_xor(ypos,    off, 64);
  }
  const int wv = tid >> 6, ln = tid & 63;
  if (ln == 0){ red[wv] = contrib; red[2+wv] = ypos; }
  __syncthreads();
  if (tid == 0){
    atomicAdd(&acc[2*img + 0], red[0] + red[1]);
    atomicAdd(&acc[2*img + 1], red[2] + red[3]);
    __threadfence();
    unsigned t = atomicAdd(done, 1u);
    if (t == (unsigned)(B_*4 - 1)){
      float s = 0.f;
      for (int b = 0; b < B_; ++b){
        float tc = atomicAdd(&acc[2*b + 0], 0.0f);
        float tn = atomicAdd(&acc[2*b + 1], 0.0f);
        s += 1.0f - __fdividef(tc, fmaxf(tn, 1.0f));
      }
      out[0] = s * (1.0f/(float)B_);
    }
  }
}

extern "C" void kernel_launch(void* const* d_in, const int* in_sizes, int n_in,
                              void* d_out, int out_size, void* d_ws, size_t ws_size,
                              hipStream_t stream){
  const float* preds   = (const float*)d_in[0];
  const float* boxes   = (const float*)d_in[1];
  const int*   targets = (const int*)d_in[2];
  float* out = (float*)d_out;

  char* ws = (char*)d_ws;
  size_t off = 0;
  auto alloc = [&](size_t nbytes)->void*{
    void* p = ws + off; off += (nbytes + 255) & ~(size_t)255; return p;
  };
  unsigned* hist = (unsigned*)alloc((size_t)B_*HB*sizeof(unsigned));
  float* scores  = (float*)alloc((size_t)B_*N_*sizeof(float));
  float* sscore  = (float*)alloc((size_t)B_*K_*sizeof(float));
  float* gbox    = (float*)alloc((size_t)B_*KP*4*sizeof(float));
  float* gtgt    = (float*)alloc((size_t)B_*K_*sizeof(float));
  float* vout    = (float*)alloc((size_t)B_*KP*sizeof(float));
  float* acc     = (float*)alloc((size_t)B_*2*sizeof(float));
  unsigned* done = (unsigned*)alloc(sizeof(unsigned));
  float* Pg      = (float*)alloc((size_t)B_*NSTRIP*64*sizeof(float)); // 9.4 MB

  hipMemsetAsync(hist, 0, (size_t)B_*HB*sizeof(unsigned), stream);
  k_scores <<<(B_*N_)/APB,   256, 0, stream>>>(preds, scores, hist);
  k_compact<<<B_,            256, 0, stream>>>(scores, hist, boxes, targets, sscore, gbox, gtgt);
  k_iou    <<<dim3(B_,8,2),  256, 0, stream>>>(gbox, Pg);
  k_nms    <<<B_,            512, 0, stream>>>(sscore, Pg, vout, acc, done);
  k_ap     <<<dim3(B_,4),    128, 0, stream>>>(vout, gtgt, acc, done, out);
}

// Round 9
// 268.813 us; speedup vs baseline: 1.0682x; 1.0682x over previous
//
#include <hip/hip_runtime.h>
#include <stdint.h>

#define B_   16
#define N_   16128
#define C_   85
#define K_   500
#define KP   512
#define APB  64            // anchors per block in k_scores (21.8 KB LDS -> 7 blocks/CU)
#define HB   4096          // histogram bins = score bits [22:11]
#define NSH  8             // histogram shards per image
#define CAND 1024
#define NSTRIP 2304        // triangular Pg strips/image

__device__ __forceinline__ float sigm(float x){
  return __fdividef(1.0f, 1.0f + __expf(-x));
}
__device__ __forceinline__ float pfun(float4 a, float4 b, float areaA){
  float x1 = fmaxf(a.x, b.x), y1 = fmaxf(a.y, b.y);
  float x2 = fminf(a.z, b.z), y2 = fminf(a.w, b.w);
  float inter = fmaxf(x2 - x1, 0.f) * fmaxf(y2 - y1, 0.f);
  float areaB = fmaxf(b.z - b.x, 0.f) * fmaxf(b.w - b.y, 0.f);
  float uni = areaA + areaB - inter;
  float iou = __fdividef(inter, fmaxf(uni, 1e-9f));
  return __fdividef(1.0f, 1.0f + __expf((0.4f - iou) * 10.0f));
}
__device__ __forceinline__ unsigned binof(unsigned sb){ return (sb >> 11) & (HB-1); }
__device__ __forceinline__ int stripbase(int i){ int w = i >> 6; return (w+1)*(i - 32*w); }

// ---------------- Stage 1: scores + sharded-histogram ----------------
// hist layout: [img][bin][shard]  (shard = blockIdx & 7) -> no hot-address chains
__global__ __launch_bounds__(256) void k_scores(const float* __restrict__ preds,
                                                float* __restrict__ scores,
                                                unsigned* __restrict__ hist){
  __shared__ float lds[APB*C_];            // 5440 floats = 1360 float4
  const int tid = threadIdx.x;
  const size_t blockBase = (size_t)blockIdx.x * (APB*C_);
  const float4* g4 = (const float4*)(preds + blockBase);
  float4* l4 = (float4*)lds;

  // all loads issued first (independent), then all LDS writes: one vmcnt drain
  float4 t[5];
  #pragma unroll
  for (int k = 0; k < 5; ++k) t[k] = g4[tid + k*256];
  const bool extra = (tid < 80);           // 1360 - 1280 = 80 tail float4s
  float4 tx = extra ? g4[1280 + tid] : make_float4(0.f,0.f,0.f,0.f);
  #pragma unroll
  for (int k = 0; k < 5; ++k) l4[tid + k*256] = t[k];
  if (extra) l4[1280 + tid] = tx;
  __syncthreads();

  if (tid < APB){
    const float* row = lds + tid*C_;
    float m = row[1];
    #pragma unroll
    for (int c=2; c<C_; ++c) m = fmaxf(m, row[c]);
    const int g = blockIdx.x*APB + tid;
    scores[g] = m;
    const int img   = g / N_;
    const int shard = blockIdx.x & (NSH-1);
    atomicAdd(&hist[(img*HB + binof(__float_as_uint(m)))*NSH + shard], 1u);
  }
}

// ---------------- Stage 2: exact top-500: cutoff from hist, compact, rank-sort ----
__global__ __launch_bounds__(256) void k_compact(const float* __restrict__ scores,
                                                 const unsigned* __restrict__ hist,
                                                 const float* __restrict__ boxes,
                                                 const int*   __restrict__ targets,
                                                 float* __restrict__ sscore,  // [B][K]
                                                 float* __restrict__ gbox,    // [B][KP][4], rows>=K zero
                                                 float* __restrict__ gtgt){   // [B][K]
  __shared__ unsigned long long keybuf[CAND];   // 8 KB
  __shared__ unsigned long long sorted[KP];     // 4 KB
  __shared__ unsigned part[256];
  __shared__ unsigned s_bsel;
  __shared__ unsigned s_cnt;
  const int img = blockIdx.x;
  const int tid = threadIdx.x;
  const float* sc = scores + (size_t)img*N_;

  // thread t owns bins [16t,16t+16): sum 8 shards each (128 consecutive words)
  const unsigned* hb = hist + ((size_t)img*HB + tid*16)*NSH;
  unsigned loc[16]; unsigned psum = 0;
  #pragma unroll
  for (int q = 0; q < 16; ++q){
    unsigned v = 0;
    #pragma unroll
    for (int s = 0; s < NSH; ++s) v += hb[q*NSH + s];
    loc[q] = v; psum += v;
  }
  part[tid] = psum;
  if (tid == 0) s_cnt = 0;
  __syncthreads();
  for (int off = 1; off < 256; off <<= 1){
    unsigned add = (tid + off < 256) ? part[tid + off] : 0;
    __syncthreads();
    part[tid] += add;
    __syncthreads();
  }
  const unsigned St  = part[tid];
  const unsigned St1 = (tid < 255) ? part[tid+1] : 0;
  if (St >= K_ && (tid == 255 || St1 < K_)){
    unsigned cum = St1; int b = tid*16;
    for (int q = 15; q >= 0; --q){
      cum += loc[q];
      if (cum >= K_){ b = tid*16 + q; break; }
    }
    s_bsel = (unsigned)b;
  }
  __syncthreads();
  const unsigned bsel = s_bsel;

  for (int n = tid; n < N_; n += 256){
    unsigned sb = __float_as_uint(sc[n]);
    if (binof(sb) >= bsel){
      unsigned pos = atomicAdd(&s_cnt, 1u);
      if (pos < CAND)
        keybuf[pos] = ((unsigned long long)sb << 14) | (unsigned long long)(N_ - 1 - n);
    }
  }
  __syncthreads();
  const int cnt = (int)min(s_cnt, (unsigned)CAND);
  for (int i = tid; i < CAND; i += 256) if (i >= cnt) keybuf[i] = 0ULL;
  __syncthreads();

  // exact rank-sort (keys unique): rank = #{keys > mine}; broadcast walk
  unsigned long long myk[4];
  int myr[4] = {0,0,0,0};
  #pragma unroll
  for (int q = 0; q < 4; ++q) myk[q] = keybuf[tid + q*256];
  for (int j = 0; j < cnt; ++j){
    unsigned long long kj = keybuf[j];
    #pragma unroll
    for (int q = 0; q < 4; ++q) myr[q] += (myk[q] < kj) ? 1 : 0;
  }
  #pragma unroll
  for (int q = 0; q < 4; ++q) if (myr[q] < K_) sorted[myr[q]] = myk[q];
  __syncthreads();

  for (int r = tid; r < K_; r += 256){
    unsigned long long key = sorted[r];
    unsigned sb = (unsigned)(key >> 14);
    unsigned n  = (unsigned)(N_ - 1 - (int)(key & 0x3FFFULL));
    sscore[img*K_ + r] = __uint_as_float(sb);
    ((float4*)gbox)[img*KP + r] = ((const float4*)boxes)[(size_t)img*N_ + n];
    gtgt[img*K_ + r] = (float)targets[(size_t)img*N_ + n];
  }
  if (tid < KP - K_)
    ((float4*)gbox)[img*KP + K_ + tid] = make_float4(0.f,0.f,0.f,0.f);
}

// ---------------- Stage 3a: masked prune matrix, triangular-packed ----------------
__global__ __launch_bounds__(256) void k_iou(const float* __restrict__ gbox,
                                             float* __restrict__ Pg){
  __shared__ float4 bcol[64];
  const int img = blockIdx.x, d = blockIdx.y, half = blockIdx.z;
  const int tid = threadIdx.x;
  const int i = half*256 + tid;
  if ((half+1)*256 <= d*64) return;
  if (tid < 64) bcol[tid] = ((const float4*)gbox)[img*KP + d*64 + tid];
  __syncthreads();
  if (i < d*64) return;
  float4 bi = ((const float4*)gbox)[img*KP + i];
  const float areai = fmaxf(bi.z-bi.x,0.f)*fmaxf(bi.w-bi.y,0.f);
  float4* dst = (float4*)(Pg + ((size_t)img*NSTRIP + stripbase(i) + d)*64);
  #pragma unroll
  for (int q = 0; q < 16; ++q){
    float4 o;
    float* op = (float*)&o;
    #pragma unroll
    for (int s = 0; s < 4; ++s){
      int jj = q*4 + s;
      float p = pfun(bi, bcol[jj], areai);
      op[s] = (d*64 + jj < i) ? p : 0.0f;
    }
    dst[q] = o;
  }
}

// ---------------- Stage 3b: diff-NMS forward substitution ----------------
__global__ __launch_bounds__(512) void k_nms(const float* __restrict__ sscore,
                                             const float* __restrict__ Pg,
                                             float* __restrict__ vout,   // [B][KP]
                                             float* __restrict__ acc,    // [B][2]
                                             unsigned* __restrict__ done){
  __shared__ float vsh[KP];
  const int img  = blockIdx.x;
  const int tid  = threadIdx.x;
  const int wave = tid >> 6;

  float rr = (tid < K_) ? sscore[img*K_ + tid] : 0.0f;
  float v  = 0.0f;
  if (tid < 2) acc[2*img + tid] = 0.0f;
  if (img == 0 && tid == 2) *done = 0;

  const float* stripRow = Pg + ((size_t)img*NSTRIP + stripbase(tid))*64;

  for (int d = 0; d < 8; ++d){
    if (wave == d){
      const float4* strip = (const float4*)(stripRow + (size_t)d*64);
      float4 p4[16];
      #pragma unroll
      for (int q = 0; q < 16; ++q) p4[q] = strip[q];
      const float* p = (const float*)p4;
      #pragma unroll
      for (int j = 0; j < 64; ++j){
        float c = fminf(fmaxf(rr, 0.0f), 1.0f);
        float vj = __int_as_float(__builtin_amdgcn_readlane(__float_as_int(c), j));
        rr -= p[j] * vj;
      }
      v = fminf(fmaxf(rr, 0.0f), 1.0f);
      vsh[tid] = v;
    }
    __syncthreads();
    if (wave > d){
      const float4* strip = (const float4*)(stripRow + (size_t)d*64);
      const float4* vv = (const float4*)(vsh + d*64);
      float s0 = 0.f, s1 = 0.f;
      #pragma unroll
      for (int q = 0; q < 16; ++q){
        float4 pq = strip[q];
        float4 vq = vv[q];
        s0 += pq.x*vq.x + pq.y*vq.y;
        s1 += pq.z*vq.z + pq.w*vq.w;
      }
      rr -= (s0 + s1);
    }
  }
  vout[img*KP + tid] = v;
}

// ---------------- Stage 4+5: AP loss + fused final reduction ----------------
__global__ __launch_bounds__(128) void k_ap(const float* __restrict__ vout,
                                            const float* __restrict__ gtgt,
                                            float* __restrict__ acc,
                                            unsigned* __restrict__ done,
                                            float* __restrict__ out){
  __shared__ float vls[K_];
  __shared__ float yls[K_];
  __shared__ float red[4];
  const int img = blockIdx.x;
  const int seg = blockIdx.y;
  const int tid = threadIdx.x;

  for (int j = tid; j < K_; j += 128){
    vls[j] = vout[img*KP + j];
    yls[j] = gtgt[img*K_ + j];
  }
  __syncthreads();

  const int i = seg*125 + tid;
  float contrib = 0.f, ypos = 0.f;
  if (tid < 125){
    const float vi = vls[i];
    const float yi = yls[i];
    float rank = 0.f, posr = 0.f;
    #pragma unroll 4
    for (int j = 0; j < K_; ++j){
      float h = sigm((vls[j] - vi) * 20.0f);
      float hm = (j == i) ? 0.0f : h;
      rank += hm;
      posr += hm * yls[j];
    }
    float prec = __fdividef(1.0f + posr, 1.0f + rank);
    contrib = prec * yi;
    ypos = yi;
  }
  #pragma unroll
  for (int off = 32; off > 0; off >>= 1){
    contrib += __shfl_xor(contrib, off, 64);
    ypos    += __shfl_xor(ypos,    off, 64);
  }
  const int wv = tid >> 6, ln = tid & 63;
  if (ln == 0){ red[wv] = contrib; red[2+wv] = ypos; }
  __syncthreads();
  if (tid == 0){
    atomicAdd(&acc[2*img + 0], red[0] + red[1]);
    atomicAdd(&acc[2*img + 1], red[2] + red[3]);
    __threadfence();
    unsigned t = atomicAdd(done, 1u);
    if (t == (unsigned)(B_*4 - 1)){
      float s = 0.f;
      for (int b = 0; b < B_; ++b){
        float tc = atomicAdd(&acc[2*b + 0], 0.0f);
        float tn = atomicAdd(&acc[2*b + 1], 0.0f);
        s += 1.0f - __fdividef(tc, fmaxf(tn, 1.0f));
      }
      out[0] = s * (1.0f/(float)B_);
    }
  }
}

extern "C" void kernel_launch(void* const* d_in, const int* in_sizes, int n_in,
                              void* d_out, int out_size, void* d_ws, size_t ws_size,
                              hipStream_t stream){
  const float* preds   = (const float*)d_in[0];
  const float* boxes   = (const float*)d_in[1];
  const int*   targets = (const int*)d_in[2];
  float* out = (float*)d_out;

  char* ws = (char*)d_ws;
  size_t off = 0;
  auto alloc = [&](size_t nbytes)->void*{
    void* p = ws + off; off += (nbytes + 255) & ~(size_t)255; return p;
  };
  unsigned* hist = (unsigned*)alloc((size_t)B_*HB*NSH*sizeof(unsigned)); // 2 MB
  float* scores  = (float*)alloc((size_t)B_*N_*sizeof(float));
  float* sscore  = (float*)alloc((size_t)B_*K_*sizeof(float));
  float* gbox    = (float*)alloc((size_t)B_*KP*4*sizeof(float));
  float* gtgt    = (float*)alloc((size_t)B_*K_*sizeof(float));
  float* vout    = (float*)alloc((size_t)B_*KP*sizeof(float));
  float* acc     = (float*)alloc((size_t)B_*2*sizeof(float));
  unsigned* done = (unsigned*)alloc(sizeof(unsigned));
  float* Pg      = (float*)alloc((size_t)B_*NSTRIP*64*sizeof(float)); // 9.4 MB

  hipMemsetAsync(hist, 0, (size_t)B_*HB*NSH*sizeof(unsigned), stream);
  k_scores <<<(B_*N_)/APB,   256, 0, stream>>>(preds, scores, hist);
  k_compact<<<B_,            256, 0, stream>>>(scores, hist, boxes, targets, sscore, gbox, gtgt);
  k_iou    <<<dim3(B_,8,2),  256, 0, stream>>>(gbox, Pg);
  k_nms    <<<B_,            512, 0, stream>>>(sscore, Pg, vout, acc, done);
  k_ap     <<<dim3(B_,4),    128, 0, stream>>>(vout, gtgt, acc, done, out);
}